// Round 1
// baseline (910.807 us; speedup 1.0000x reference)
//
#include <hip/hip_runtime.h>

#define N_NODES 8192
#define DIM     128
#define MARGIN  1.0f

// pass-1 tiling
#define BM 64
#define BN 64
#define CHUNK 1024                 // columns handled per block
#define TILES_PER_CHUNK (CHUNK / BN)
#define A_STRIDE (DIM + 4)         // 132: 4*tm bank offset -> conflict-free A reads
#define B_STRIDE (64 + 4)          // 68: half-K B tile, 4*tn bank offset

// ---------------------------------------------------------------------------
// Kernel 0: per-row squared norms + workspace init (min_d2 = +inf, total/count = 0)
// one wave per row (4 rows / 256-thread block)
__global__ void sq_init_kernel(const float* __restrict__ x,
                               float* __restrict__ sq,
                               unsigned int* __restrict__ min_d2,
                               double* __restrict__ total,
                               unsigned int* __restrict__ count) {
    int row  = blockIdx.x * 4 + (threadIdx.x >> 6);
    int lane = threadIdx.x & 63;
    const float* p = x + (size_t)row * DIM;
    float v0 = p[lane], v1 = p[lane + 64];
    float s = v0 * v0 + v1 * v1;
    #pragma unroll
    for (int off = 32; off > 0; off >>= 1) s += __shfl_down(s, off);
    if (lane == 0) {
        sq[row] = s;
        min_d2[row] = 0x7f800000u;   // +inf bits
    }
    if (blockIdx.x == 0 && threadIdx.x == 0) { *total = 0.0; *count = 0u; }
}

// ---------------------------------------------------------------------------
// Kernel 1: fused X·X^T tile + hardest-negative (min d^2 over different-community cols)
// block: 256 threads = 16x16 thread grid, 4x4 micro-tile -> 64x64 output tile.
// thread rows: m = tm + 16*r, cols: n = tn + 16*s (stride-16 spread keeps LDS
// fragment reads conflict-free).
__global__ __launch_bounds__(256, 2)
void minneg_kernel(const float* __restrict__ x,
                   const int* __restrict__ comm,
                   const float* __restrict__ sq,
                   unsigned int* __restrict__ min_d2) {
    __shared__ float As[BM][A_STRIDE];   // full K resident for row tile
    __shared__ float Bs[BN][B_STRIDE];   // half K at a time

    const int tid = threadIdx.x;
    const int tm = tid >> 4;     // 0..15
    const int tn = tid & 15;     // 0..15
    const int i0 = blockIdx.x * BM;
    const int j0 = blockIdx.y * CHUNK;

    // stage A tile: 64 rows x 128 cols, coalesced float4
    {
        const float4* src = (const float4*)(x + (size_t)i0 * DIM);
        #pragma unroll
        for (int it = 0; it < 8; ++it) {
            int g = tid + it * 256;          // 0..2047
            int r = g >> 5, c = g & 31;
            *(float4*)&As[r][c * 4] = src[r * 32 + c];
        }
    }

    int   ci[4];
    float sqi[4];
    float minv[4];
    #pragma unroll
    for (int r = 0; r < 4; ++r) {
        int i = i0 + tm + 16 * r;
        ci[r]  = comm[i];
        sqi[r] = sq[i];
        minv[r] = __uint_as_float(0x7f800000u);  // +inf
    }

    for (int t = 0; t < TILES_PER_CHUNK; ++t) {
        const int jb = j0 + t * BN;

        float acc[4][4];
        #pragma unroll
        for (int r = 0; r < 4; ++r)
            #pragma unroll
            for (int s = 0; s < 4; ++s) acc[r][s] = 0.f;

        #pragma unroll
        for (int kh = 0; kh < 2; ++kh) {
            __syncthreads();   // previous Bs reads done
            // stage B half-tile: 64 rows x 64 cols
            #pragma unroll
            for (int it = 0; it < 4; ++it) {
                int g = tid + it * 256;      // 0..1023
                int r = g >> 4, c = g & 15;
                *(float4*)&Bs[r][c * 4] =
                    *(const float4*)&x[(size_t)(jb + r) * DIM + kh * 64 + c * 4];
            }
            __syncthreads();

            #pragma unroll 4
            for (int k4 = 0; k4 < 16; ++k4) {
                float4 a[4], b[4];
                #pragma unroll
                for (int r = 0; r < 4; ++r)
                    a[r] = *(const float4*)&As[tm + 16 * r][kh * 64 + k4 * 4];
                #pragma unroll
                for (int s = 0; s < 4; ++s)
                    b[s] = *(const float4*)&Bs[tn + 16 * s][k4 * 4];
                #pragma unroll
                for (int r = 0; r < 4; ++r)
                    #pragma unroll
                    for (int s = 0; s < 4; ++s)
                        acc[r][s] += a[r].x * b[s].x + a[r].y * b[s].y +
                                     a[r].z * b[s].z + a[r].w * b[s].w;
            }
        }

        // epilogue: d2 = sq_i + sq_j - 2*dot, clamp, min over negatives
        #pragma unroll
        for (int s = 0; s < 4; ++s) {
            int j = jb + tn + 16 * s;
            int cj = comm[j];
            float sqj = sq[j];
            #pragma unroll
            for (int r = 0; r < 4; ++r) {
                float d2 = fmaxf(sqi[r] + sqj - 2.f * acc[r][s], 0.f);
                if (cj != ci[r]) minv[r] = fminf(minv[r], d2);
            }
        }
    }

    // block reduce the per-row mins across the 16 tn groups (overlay on Bs)
    float (*red)[17] = (float (*)[17])Bs;
    __syncthreads();
    #pragma unroll
    for (int r = 0; r < 4; ++r) red[tm + 16 * r][tn] = minv[r];
    __syncthreads();
    if (tid < BM) {
        float m = red[tid][0];
        #pragma unroll
        for (int c = 1; c < 16; ++c) m = fminf(m, red[tid][c]);
        atomicMin(&min_d2[i0 + tid], __float_as_uint(m));  // d2 >= 0 -> bit order ok
    }
}

// ---------------------------------------------------------------------------
// Kernel 2: positive pairs only (~82 per anchor). One block per anchor row.
__global__ __launch_bounds__(256)
void pos_kernel(const float* __restrict__ x,
                const int* __restrict__ comm,
                const float* __restrict__ sq,
                const unsigned int* __restrict__ min_d2,
                double* __restrict__ total,
                unsigned int* __restrict__ count) {
    const int i = blockIdx.x;
    __shared__ float xi[DIM];
    __shared__ float ws_s[4];
    __shared__ unsigned int wc_s[4];

    unsigned int mbits = min_d2[i];
    if (mbits == 0x7f800000u) return;   // no negatives -> row contributes nothing
    float md2 = __uint_as_float(mbits);
    float minneg = md2 > 0.f ? sqrtf(md2) : 0.f;

    const int tid = threadIdx.x;
    const int ci  = comm[i];
    const float sqi = sq[i];

    if (tid < DIM) xi[tid] = x[(size_t)i * DIM + tid];
    __syncthreads();

    float lsum = 0.f;
    unsigned int lcnt = 0u;
    const float4* xi4 = (const float4*)xi;
    for (int j = tid; j < N_NODES; j += 256) {
        if (comm[j] == ci && j != i) {
            const float4* xj = (const float4*)(x + (size_t)j * DIM);
            float dot = 0.f;
            #pragma unroll
            for (int k = 0; k < DIM / 4; ++k) {
                float4 a = xi4[k], b = xj[k];
                dot += a.x * b.x + a.y * b.y + a.z * b.z + a.w * b.w;
            }
            float d2 = fmaxf(sqi + sq[j] - 2.f * dot, 0.f);
            float dist = d2 > 0.f ? sqrtf(d2) : 0.f;
            lsum += fmaxf(dist - minneg + MARGIN, 0.f);
            lcnt += 1u;   // count ALL valid pairs, even tl==0
        }
    }
    #pragma unroll
    for (int off = 32; off > 0; off >>= 1) {
        lsum += __shfl_down(lsum, off);
        lcnt += __shfl_down(lcnt, off);
    }
    int lane = tid & 63, w = tid >> 6;
    if (lane == 0) { ws_s[w] = lsum; wc_s[w] = lcnt; }
    __syncthreads();
    if (tid == 0) {
        float s = ws_s[0] + ws_s[1] + ws_s[2] + ws_s[3];
        unsigned int c = wc_s[0] + wc_s[1] + wc_s[2] + wc_s[3];
        if (c > 0u) {
            atomicAdd(total, (double)s);
            atomicAdd(count, c);
        }
    }
}

// ---------------------------------------------------------------------------
__global__ void finalize_kernel(const double* __restrict__ total,
                                const unsigned int* __restrict__ count,
                                float* __restrict__ out) {
    if (threadIdx.x == 0)
        out[0] = (*count > 0u) ? (float)(*total / (double)(*count)) : 0.f;
}

// ---------------------------------------------------------------------------
extern "C" void kernel_launch(void* const* d_in, const int* in_sizes, int n_in,
                              void* d_out, int out_size, void* d_ws, size_t ws_size,
                              hipStream_t stream) {
    const float* x    = (const float*)d_in[0];
    const int*   comm = (const int*)d_in[1];
    float*       out  = (float*)d_out;

    // workspace layout: [double total][uint count][pad to 16][float sq N][uint min_d2 N]
    char* ws = (char*)d_ws;
    double*       total  = (double*)ws;
    unsigned int* count  = (unsigned int*)(ws + 8);
    float*        sq     = (float*)(ws + 16);
    unsigned int* min_d2 = (unsigned int*)(ws + 16 + N_NODES * sizeof(float));

    sq_init_kernel<<<N_NODES / 4, 256, 0, stream>>>(x, sq, min_d2, total, count);

    dim3 g1(N_NODES / BM, N_NODES / CHUNK);   // 128 x 8 = 1024 blocks
    minneg_kernel<<<g1, 256, 0, stream>>>(x, comm, sq, min_d2);

    pos_kernel<<<N_NODES, 256, 0, stream>>>(x, comm, sq, min_d2, total, count);

    finalize_kernel<<<1, 64, 0, stream>>>(total, count, out);
}

// Round 2
// 611.305 us; speedup vs baseline: 1.4899x; 1.4899x over previous
//
#include <hip/hip_runtime.h>

#define N_NODES 8192
#define DIM     128
#define N_COMM  100
#define MARGIN  1.0f

// pass-1 tiling
#define BM 64
#define BN 64
#define CHUNK 1024                 // columns handled per block
#define TILES_PER_CHUNK (CHUNK / BN)
#define A_STRIDE (DIM + 4)         // 132: 4*tm bank offset -> conflict-free A reads
#define B_STRIDE (64 + 4)          // 68: half-K B tile, 4*tn bank offset

// ---------------------------------------------------------------------------
// Kernel 0: per-row squared norms + workspace init (min_d2 = +inf, total/count = 0)
// one wave per row (4 rows / 256-thread block)
__global__ void sq_init_kernel(const float* __restrict__ x,
                               float* __restrict__ sq,
                               unsigned int* __restrict__ min_d2,
                               double* __restrict__ total,
                               unsigned int* __restrict__ count) {
    int row  = blockIdx.x * 4 + (threadIdx.x >> 6);
    int lane = threadIdx.x & 63;
    const float* p = x + (size_t)row * DIM;
    float v0 = p[lane], v1 = p[lane + 64];
    float s = v0 * v0 + v1 * v1;
    #pragma unroll
    for (int off = 32; off > 0; off >>= 1) s += __shfl_down(s, off);
    if (lane == 0) {
        sq[row] = s;
        min_d2[row] = 0x7f800000u;   // +inf bits
    }
    if (blockIdx.x == 0 && threadIdx.x == 0) { *total = 0.0; *count = 0u; }
}

// ---------------------------------------------------------------------------
// Kernel 0b: single-block community bucketing (counts -> offsets -> compacted
// member list). N=8192, C=100 -> trivial; LDS atomics, one dispatch.
__global__ __launch_bounds__(256)
void bucket_kernel(const int* __restrict__ comm,
                   int* __restrict__ offs,      // [N_COMM+1]
                   int* __restrict__ members) { // [N_NODES]
    __shared__ int scnt[N_COMM];
    __shared__ int scur[N_COMM];
    const int tid = threadIdx.x;
    for (int c = tid; c < N_COMM; c += 256) scnt[c] = 0;
    __syncthreads();
    for (int i = tid; i < N_NODES; i += 256) atomicAdd(&scnt[comm[i]], 1);
    __syncthreads();
    if (tid == 0) {
        int acc = 0;
        for (int c = 0; c < N_COMM; ++c) { scur[c] = acc; offs[c] = acc; acc += scnt[c]; }
        offs[N_COMM] = acc;
    }
    __syncthreads();
    for (int i = tid; i < N_NODES; i += 256) {
        int p = atomicAdd(&scur[comm[i]], 1);
        members[p] = i;
    }
}

// ---------------------------------------------------------------------------
// Kernel 1: fused X·X^T tile + hardest-negative (min d^2 over different-community cols)
// UNCHANGED from R1 — it becomes the top dispatch so we get its counters.
__global__ __launch_bounds__(256, 2)
void minneg_kernel(const float* __restrict__ x,
                   const int* __restrict__ comm,
                   const float* __restrict__ sq,
                   unsigned int* __restrict__ min_d2) {
    __shared__ float As[BM][A_STRIDE];   // full K resident for row tile
    __shared__ float Bs[BN][B_STRIDE];   // half K at a time

    const int tid = threadIdx.x;
    const int tm = tid >> 4;     // 0..15
    const int tn = tid & 15;     // 0..15
    const int i0 = blockIdx.x * BM;
    const int j0 = blockIdx.y * CHUNK;

    // stage A tile: 64 rows x 128 cols, coalesced float4
    {
        const float4* src = (const float4*)(x + (size_t)i0 * DIM);
        #pragma unroll
        for (int it = 0; it < 8; ++it) {
            int g = tid + it * 256;          // 0..2047
            int r = g >> 5, c = g & 31;
            *(float4*)&As[r][c * 4] = src[r * 32 + c];
        }
    }

    int   ci[4];
    float sqi[4];
    float minv[4];
    #pragma unroll
    for (int r = 0; r < 4; ++r) {
        int i = i0 + tm + 16 * r;
        ci[r]  = comm[i];
        sqi[r] = sq[i];
        minv[r] = __uint_as_float(0x7f800000u);  // +inf
    }

    for (int t = 0; t < TILES_PER_CHUNK; ++t) {
        const int jb = j0 + t * BN;

        float acc[4][4];
        #pragma unroll
        for (int r = 0; r < 4; ++r)
            #pragma unroll
            for (int s = 0; s < 4; ++s) acc[r][s] = 0.f;

        #pragma unroll
        for (int kh = 0; kh < 2; ++kh) {
            __syncthreads();   // previous Bs reads done
            // stage B half-tile: 64 rows x 64 cols
            #pragma unroll
            for (int it = 0; it < 4; ++it) {
                int g = tid + it * 256;      // 0..1023
                int r = g >> 4, c = g & 15;
                *(float4*)&Bs[r][c * 4] =
                    *(const float4*)&x[(size_t)(jb + r) * DIM + kh * 64 + c * 4];
            }
            __syncthreads();

            #pragma unroll 4
            for (int k4 = 0; k4 < 16; ++k4) {
                float4 a[4], b[4];
                #pragma unroll
                for (int r = 0; r < 4; ++r)
                    a[r] = *(const float4*)&As[tm + 16 * r][kh * 64 + k4 * 4];
                #pragma unroll
                for (int s = 0; s < 4; ++s)
                    b[s] = *(const float4*)&Bs[tn + 16 * s][k4 * 4];
                #pragma unroll
                for (int r = 0; r < 4; ++r)
                    #pragma unroll
                    for (int s = 0; s < 4; ++s)
                        acc[r][s] += a[r].x * b[s].x + a[r].y * b[s].y +
                                     a[r].z * b[s].z + a[r].w * b[s].w;
            }
        }

        // epilogue: d2 = sq_i + sq_j - 2*dot, clamp, min over negatives
        #pragma unroll
        for (int s = 0; s < 4; ++s) {
            int j = jb + tn + 16 * s;
            int cj = comm[j];
            float sqj = sq[j];
            #pragma unroll
            for (int r = 0; r < 4; ++r) {
                float d2 = fmaxf(sqi[r] + sqj - 2.f * acc[r][s], 0.f);
                if (cj != ci[r]) minv[r] = fminf(minv[r], d2);
            }
        }
    }

    // block reduce the per-row mins across the 16 tn groups (overlay on Bs)
    float (*red)[17] = (float (*)[17])Bs;
    __syncthreads();
    #pragma unroll
    for (int r = 0; r < 4; ++r) red[tm + 16 * r][tn] = minv[r];
    __syncthreads();
    if (tid < BM) {
        float m = red[tid][0];
        #pragma unroll
        for (int c = 1; c < 16; ++c) m = fminf(m, red[tid][c]);
        atomicMin(&min_d2[i0 + tid], __float_as_uint(m));  // d2 >= 0 -> bit order ok
    }
}

// ---------------------------------------------------------------------------
// Kernel 2 (v2): wave-per-anchor over the COMPACTED positive list.
// Lane l holds xi[l], xi[l+64]; per positive j: coalesced xj loads, direct
// (xi-xj)^2 partial, butterfly reduce (all lanes end with dot). No divergence.
__global__ __launch_bounds__(256)
void pos2_kernel(const float* __restrict__ x,
                 const int* __restrict__ comm,
                 const unsigned int* __restrict__ min_d2,
                 const int* __restrict__ offs,
                 const int* __restrict__ members,
                 double* __restrict__ total,
                 unsigned int* __restrict__ count) {
    const int i    = blockIdx.x * 4 + (threadIdx.x >> 6);   // anchor
    const int lane = threadIdx.x & 63;

    unsigned int mbits = min_d2[i];
    if (mbits == 0x7f800000u) return;      // no negatives: row contributes nothing
    float md2 = __uint_as_float(mbits);
    float minneg = md2 > 0.f ? sqrtf(md2) : 0.f;

    const int c   = comm[i];
    const int beg = offs[c], end = offs[c + 1];
    const int npos = end - beg - 1;        // positives for this anchor
    if (npos <= 0) return;

    const float xi0 = x[(size_t)i * DIM + lane];
    const float xi1 = x[(size_t)i * DIM + 64 + lane];

    float asum = 0.f;
    for (int p = beg; p < end; ++p) {
        int j = members[p];
        if (j == i) continue;              // wave-uniform
        const float* xj = x + (size_t)j * DIM;
        float d0 = xi0 - xj[lane];
        float d1 = xi1 - xj[lane + 64];
        float part = d0 * d0 + d1 * d1;
        #pragma unroll
        for (int off = 1; off < 64; off <<= 1) part += __shfl_xor(part, off);
        float dist = sqrtf(part);          // part >= 0 by construction
        asum += fmaxf(dist - minneg + MARGIN, 0.f);
    }
    if (lane == 0) {
        atomicAdd(total, (double)asum);
        atomicAdd(count, (unsigned int)npos);   // count includes tl==0 pairs
    }
}

// ---------------------------------------------------------------------------
__global__ void finalize_kernel(const double* __restrict__ total,
                                const unsigned int* __restrict__ count,
                                float* __restrict__ out) {
    if (threadIdx.x == 0)
        out[0] = (*count > 0u) ? (float)(*total / (double)(*count)) : 0.f;
}

// ---------------------------------------------------------------------------
extern "C" void kernel_launch(void* const* d_in, const int* in_sizes, int n_in,
                              void* d_out, int out_size, void* d_ws, size_t ws_size,
                              hipStream_t stream) {
    const float* x    = (const float*)d_in[0];
    const int*   comm = (const int*)d_in[1];
    float*       out  = (float*)d_out;

    // workspace layout (bytes):
    // [0]      double total
    // [8]      uint count
    // [16]     float sq[8192]          (32 KB)
    // [+32768] uint min_d2[8192]       (32 KB)
    // [+]      int offs[N_COMM+1]
    // [+512]   int members[8192]       (32 KB)
    char* ws = (char*)d_ws;
    double*       total   = (double*)ws;
    unsigned int* count   = (unsigned int*)(ws + 8);
    float*        sq      = (float*)(ws + 16);
    unsigned int* min_d2  = (unsigned int*)(ws + 16 + 32768);
    int*          offs    = (int*)(ws + 16 + 65536);
    int*          members = (int*)(ws + 16 + 65536 + 512);

    sq_init_kernel<<<N_NODES / 4, 256, 0, stream>>>(x, sq, min_d2, total, count);

    bucket_kernel<<<1, 256, 0, stream>>>(comm, offs, members);

    dim3 g1(N_NODES / BM, N_NODES / CHUNK);   // 128 x 8 = 1024 blocks
    minneg_kernel<<<g1, 256, 0, stream>>>(x, comm, sq, min_d2);

    pos2_kernel<<<N_NODES / 4, 256, 0, stream>>>(x, comm, min_d2, offs, members,
                                                 total, count);

    finalize_kernel<<<1, 64, 0, stream>>>(total, count, out);
}

// Round 3
// 217.384 us; speedup vs baseline: 4.1898x; 2.8121x over previous
//
#include <hip/hip_runtime.h>

#define N_NODES 8192
#define DIM     128
#define N_COMM  100
#define MARGIN  1.0f

// minneg_mfma tiling: 128x128 block tile, 4 waves of 64x64, mfma 32x32x16 bf16
#define LDS_K   64                // K staged per half
#define LDS_STR 72                // bf16 stride: 144 B = 9*16B -> aligned + conflict-free b128

typedef __attribute__((ext_vector_type(8)))  short bf16x8;
typedef __attribute__((ext_vector_type(16))) float f32x16;

__device__ inline unsigned short f32_to_bf16_rne(float f) {
    unsigned u = __float_as_uint(f);
    unsigned r = u + 0x7fffu + ((u >> 16) & 1u);
    return (unsigned short)(r >> 16);
}
__device__ inline float bf16_to_f32(unsigned short h) {
    return __uint_as_float(((unsigned)h) << 16);
}

// ---------------------------------------------------------------------------
// Kernel 0: bf16 hi/lo split + row squared norms + min_d2 init. Wave per row.
__global__ __launch_bounds__(256)
void convert_sq_kernel(const float* __restrict__ x,
                       unsigned short* __restrict__ xhi,
                       unsigned short* __restrict__ xlo,
                       float* __restrict__ sq,
                       unsigned int* __restrict__ min_d2) {
    int row  = blockIdx.x * 4 + (threadIdx.x >> 6);
    int lane = threadIdx.x & 63;
    const float* p = x + (size_t)row * DIM;
    float v0 = p[lane], v1 = p[lane + 64];
    unsigned short h0 = f32_to_bf16_rne(v0), h1 = f32_to_bf16_rne(v1);
    unsigned short l0 = f32_to_bf16_rne(v0 - bf16_to_f32(h0));
    unsigned short l1 = f32_to_bf16_rne(v1 - bf16_to_f32(h1));
    size_t base = (size_t)row * DIM;
    xhi[base + lane] = h0;  xhi[base + 64 + lane] = h1;
    xlo[base + lane] = l0;  xlo[base + 64 + lane] = l1;
    float s = v0 * v0 + v1 * v1;
    #pragma unroll
    for (int off = 32; off > 0; off >>= 1) s += __shfl_down(s, off);
    if (lane == 0) {
        sq[row] = s;
        min_d2[row] = 0x7f800000u;   // +inf bits
    }
}

// ---------------------------------------------------------------------------
// Kernel 0b: single-block community bucketing (unchanged).
__global__ __launch_bounds__(256)
void bucket_kernel(const int* __restrict__ comm,
                   int* __restrict__ offs,      // [N_COMM+1]
                   int* __restrict__ members) { // [N_NODES]
    __shared__ int scnt[N_COMM];
    __shared__ int scur[N_COMM];
    const int tid = threadIdx.x;
    for (int c = tid; c < N_COMM; c += 256) scnt[c] = 0;
    __syncthreads();
    for (int i = tid; i < N_NODES; i += 256) atomicAdd(&scnt[comm[i]], 1);
    __syncthreads();
    if (tid == 0) {
        int acc = 0;
        for (int c = 0; c < N_COMM; ++c) { scur[c] = acc; offs[c] = acc; acc += scnt[c]; }
        offs[N_COMM] = acc;
    }
    __syncthreads();
    for (int i = tid; i < N_NODES; i += 256) {
        int p = atomicAdd(&scur[comm[i]], 1);
        members[p] = i;
    }
}

// ---------------------------------------------------------------------------
// Kernel 1: MFMA X·X^T via bf16 hi/lo split; fused hardest-negative column-min.
// dot = hi·hi + hi·lo + lo·hi (lo·lo dropped, ~2^-17 relative).
// C/D layout (m74/m101): col = lane&31, row = (reg&3) + 8*(reg>>2) + 4*(lane>>5).
// A/B layout: m(or n) = lane&31, k = (lane>>5)*8 + j, 8 contiguous bf16.
__global__ __launch_bounds__(256, 2)
void minneg_mfma_kernel(const unsigned short* __restrict__ xhi,
                        const unsigned short* __restrict__ xlo,
                        const int* __restrict__ comm,
                        const float* __restrict__ sq,
                        unsigned int* __restrict__ min_d2) {
    // tiles: 0=Ahi 1=Alo 2=Bhi 3=Blo ; 4*128*72*2 B = 72 KB
    __shared__ unsigned short lds[4][128][LDS_STR];
    __shared__ unsigned int colmin[128];

    const int tid  = threadIdx.x;
    const int lane = tid & 63;
    const int w    = tid >> 6;
    const int wr   = w >> 1, wc = w & 1;    // wave position in 2x2 grid of 64x64
    const int lr   = lane & 31;             // row/col-within-32 for frags
    const int lh   = lane >> 5;             // half-wave -> k-half of fragment
    const int i0   = blockIdx.x * 128;      // A rows
    const int j0   = blockIdx.y * 128;      // B rows (= output cols)

    if (tid < 128) colmin[tid] = 0x7f800000u;

    f32x16 acc[2][2];
    #pragma unroll
    for (int g = 0; g < 2; ++g)
        #pragma unroll
        for (int h = 0; h < 2; ++h)
            #pragma unroll
            for (int e = 0; e < 16; ++e) acc[g][h][e] = 0.f;

    #pragma unroll
    for (int kh = 0; kh < 2; ++kh) {
        __syncthreads();   // protect LDS from previous iteration's readers
        // stage 4 tiles x 128 rows x 64 bf16 (16B per thread-task, 16 tasks/thread)
        #pragma unroll
        for (int it = 0; it < 16; ++it) {
            int g    = tid + it * 256;          // 0..4095
            int tile = g >> 10;                 // 0..3
            int row  = (g >> 3) & 127;
            int seg  = g & 7;
            const unsigned short* src = (tile & 1) ? xlo : xhi;
            int rbase = (tile & 2) ? j0 : i0;
            uint4 v = *(const uint4*)&src[(size_t)(rbase + row) * DIM + kh * 64 + seg * 8];
            *(uint4*)&lds[tile][row][seg * 8] = v;
        }
        __syncthreads();

        #pragma unroll
        for (int ks = 0; ks < 4; ++ks) {
            const int kb = ks * 16 + lh * 8;
            bf16x8 ahi[2], alo[2], bhi[2], blo[2];
            #pragma unroll
            for (int g = 0; g < 2; ++g) {
                ahi[g] = *(const bf16x8*)&lds[0][wr * 64 + g * 32 + lr][kb];
                alo[g] = *(const bf16x8*)&lds[1][wr * 64 + g * 32 + lr][kb];
            }
            #pragma unroll
            for (int h = 0; h < 2; ++h) {
                bhi[h] = *(const bf16x8*)&lds[2][wc * 64 + h * 32 + lr][kb];
                blo[h] = *(const bf16x8*)&lds[3][wc * 64 + h * 32 + lr][kb];
            }
            #pragma unroll
            for (int g = 0; g < 2; ++g)
                #pragma unroll
                for (int h = 0; h < 2; ++h) {
                    acc[g][h] = __builtin_amdgcn_mfma_f32_32x32x16_bf16(
                        ahi[g], bhi[h], acc[g][h], 0, 0, 0);
                    acc[g][h] = __builtin_amdgcn_mfma_f32_32x32x16_bf16(
                        ahi[g], blo[h], acc[g][h], 0, 0, 0);
                    acc[g][h] = __builtin_amdgcn_mfma_f32_32x32x16_bf16(
                        alo[g], bhi[h], acc[g][h], 0, 0, 0);
                }
        }
    }

    // ---- epilogue: d2 = sq_i + sq_j - 2*dot ; col-min over different-community rows
    // preload row comm / row sq for this thread's 32 rows (per g: 4 int4/float4)
    int   civ[2][4][4];
    float sqv[2][4][4];
    #pragma unroll
    for (int g = 0; g < 2; ++g)
        #pragma unroll
        for (int q = 0; q < 4; ++q) {
            int rb = i0 + wr * 64 + g * 32 + 4 * lh + 8 * q;
            *(int4*)&civ[g][q][0]   = *(const int4*)&comm[rb];
            *(float4*)&sqv[g][q][0] = *(const float4*)&sq[rb];
        }

    #pragma unroll
    for (int h = 0; h < 2; ++h) {
        int colt = wc * 64 + h * 32 + lr;
        int j  = j0 + colt;
        int cj = comm[j];
        float sqj = sq[j];
        float m = __uint_as_float(0x7f800000u);
        #pragma unroll
        for (int g = 0; g < 2; ++g)
            #pragma unroll
            for (int q = 0; q < 4; ++q)
                #pragma unroll
                for (int t = 0; t < 4; ++t) {
                    float d2 = sqv[g][q][t] + sqj - 2.f * acc[g][h][q * 4 + t];
                    if (civ[g][q][t] != cj) m = fminf(m, d2);
                }
        m = fminf(m, __shfl_xor(m, 32));
        if (lh == 0) atomicMin(&colmin[colt], __float_as_uint(m));
    }
    __syncthreads();
    if (tid < 128) atomicMin(&min_d2[j0 + tid], colmin[tid]);
}

// ---------------------------------------------------------------------------
// Kernel 2: positives via compacted list; per-block PARTIAL outputs (no global
// same-address atomics). Wave per anchor, 4 anchors per block.
__global__ __launch_bounds__(256)
void pos2_kernel(const float* __restrict__ x,
                 const int* __restrict__ comm,
                 const unsigned int* __restrict__ min_d2,
                 const int* __restrict__ offs,
                 const int* __restrict__ members,
                 double* __restrict__ psum,
                 unsigned int* __restrict__ pcnt) {
    __shared__ double       sred[4];
    __shared__ unsigned int cred[4];
    const int w    = threadIdx.x >> 6;
    const int lane = threadIdx.x & 63;
    const int i    = blockIdx.x * 4 + w;

    float asum = 0.f;
    int   npos = 0;

    unsigned int mbits = min_d2[i];
    if (mbits != 0x7f800000u) {            // wave-uniform
        float md2 = __uint_as_float(mbits);
        float minneg = md2 > 0.f ? sqrtf(md2) : 0.f;
        const int c   = comm[i];
        const int beg = offs[c], end = offs[c + 1];
        npos = end - beg - 1;
        if (npos > 0) {
            const float xi0 = x[(size_t)i * DIM + lane];
            const float xi1 = x[(size_t)i * DIM + 64 + lane];
            for (int p = beg; p < end; ++p) {
                int j = members[p];
                if (j == i) continue;      // wave-uniform
                const float* xj = x + (size_t)j * DIM;
                float d0 = xi0 - xj[lane];
                float d1 = xi1 - xj[lane + 64];
                float part = d0 * d0 + d1 * d1;
                #pragma unroll
                for (int off = 1; off < 64; off <<= 1) part += __shfl_xor(part, off);
                float dist = sqrtf(part);
                asum += fmaxf(dist - minneg + MARGIN, 0.f);
            }
        } else {
            npos = 0;
        }
    }
    if (lane == 0) { sred[w] = (double)asum; cred[w] = (unsigned int)npos; }
    __syncthreads();
    if (threadIdx.x == 0) {
        psum[blockIdx.x] = sred[0] + sred[1] + sred[2] + sred[3];
        pcnt[blockIdx.x] = cred[0] + cred[1] + cred[2] + cred[3];
    }
}

// ---------------------------------------------------------------------------
// Kernel 3: reduce 2048 block partials -> final mean.
__global__ __launch_bounds__(256)
void finalize_kernel(const double* __restrict__ psum,
                     const unsigned int* __restrict__ pcnt,
                     float* __restrict__ out) {
    __shared__ double       ds[256];
    __shared__ unsigned int cs[256];
    const int t = threadIdx.x;
    double s = 0.0; unsigned int c = 0u;
    for (int b = t; b < 2048; b += 256) { s += psum[b]; c += pcnt[b]; }
    ds[t] = s; cs[t] = c;
    __syncthreads();
    for (int off = 128; off > 0; off >>= 1) {
        if (t < off) { ds[t] += ds[t + off]; cs[t] += cs[t + off]; }
        __syncthreads();
    }
    if (t == 0) out[0] = (cs[0] > 0u) ? (float)(ds[0] / (double)cs[0]) : 0.f;
}

// ---------------------------------------------------------------------------
extern "C" void kernel_launch(void* const* d_in, const int* in_sizes, int n_in,
                              void* d_out, int out_size, void* d_ws, size_t ws_size,
                              hipStream_t stream) {
    const float* x    = (const float*)d_in[0];
    const int*   comm = (const int*)d_in[1];
    float*       out  = (float*)d_out;

    // workspace layout (bytes):
    //      0 float  sq[8192]              32768
    //  32768 uint   min_d2[8192]          32768
    //  65536 int    offs[101]               512 (padded)
    //  66048 int    members[8192]         32768
    //  98816 double psum[2048]            16384
    // 115200 uint   pcnt[2048]             8192
    // 123392 ushort xhi[8192*128]       2097152
    // 2220544 ushort xlo[8192*128]      2097152   (total ~4.2 MB)
    char* ws = (char*)d_ws;
    float*          sq      = (float*)(ws);
    unsigned int*   min_d2  = (unsigned int*)(ws + 32768);
    int*            offs    = (int*)(ws + 65536);
    int*            members = (int*)(ws + 66048);
    double*         psum    = (double*)(ws + 98816);
    unsigned int*   pcnt    = (unsigned int*)(ws + 115200);
    unsigned short* xhi     = (unsigned short*)(ws + 123392);
    unsigned short* xlo     = (unsigned short*)(ws + 2220544);

    convert_sq_kernel<<<N_NODES / 4, 256, 0, stream>>>(x, xhi, xlo, sq, min_d2);

    bucket_kernel<<<1, 256, 0, stream>>>(comm, offs, members);

    dim3 g1(N_NODES / 128, N_NODES / 128);   // 64 x 64 = 4096 blocks
    minneg_mfma_kernel<<<g1, 256, 0, stream>>>(xhi, xlo, comm, sq, min_d2);

    pos2_kernel<<<N_NODES / 4, 256, 0, stream>>>(x, comm, min_d2, offs, members,
                                                 psum, pcnt);

    finalize_kernel<<<1, 256, 0, stream>>>(psum, pcnt, out);
}

// Round 4
// 141.620 us; speedup vs baseline: 6.4314x; 1.5350x over previous
//
#include <hip/hip_runtime.h>

#define N_NODES 8192
#define DIM     128
#define N_COMM  100
#define MARGIN  1.0f

// MFMA tiling: 128x128 block tile, 4 waves of 64x64, mfma 32x32x16 bf16
#define LDS_STR 72                // bf16 stride: 144 B = 9*16B -> aligned + conflict-free b128
#define RP_STR  68                // row-min partial stride (floats): 272 B = 17*16B

typedef __attribute__((ext_vector_type(8)))  short bf16x8;
typedef __attribute__((ext_vector_type(16))) float f32x16;

__device__ inline unsigned short f32_to_bf16_rne(float f) {
    unsigned u = __float_as_uint(f);
    unsigned r = u + 0x7fffu + ((u >> 16) & 1u);
    return (unsigned short)(r >> 16);
}
__device__ inline float bf16_to_f32(unsigned short h) {
    return __uint_as_float(((unsigned)h) << 16);
}

// ---------------------------------------------------------------------------
// Kernel 0: bf16 hi/lo split + row squared norms + min_d2 init. Wave per row.
__global__ __launch_bounds__(256)
void convert_sq_kernel(const float* __restrict__ x,
                       unsigned short* __restrict__ xhi,
                       unsigned short* __restrict__ xlo,
                       float* __restrict__ sq,
                       unsigned int* __restrict__ min_d2) {
    int row  = blockIdx.x * 4 + (threadIdx.x >> 6);
    int lane = threadIdx.x & 63;
    const float* p = x + (size_t)row * DIM;
    float v0 = p[lane], v1 = p[lane + 64];
    unsigned short h0 = f32_to_bf16_rne(v0), h1 = f32_to_bf16_rne(v1);
    unsigned short l0 = f32_to_bf16_rne(v0 - bf16_to_f32(h0));
    unsigned short l1 = f32_to_bf16_rne(v1 - bf16_to_f32(h1));
    size_t base = (size_t)row * DIM;
    xhi[base + lane] = h0;  xhi[base + 64 + lane] = h1;
    xlo[base + lane] = l0;  xlo[base + 64 + lane] = l1;
    float s = v0 * v0 + v1 * v1;
    #pragma unroll
    for (int off = 32; off > 0; off >>= 1) s += __shfl_down(s, off);
    if (lane == 0) {
        sq[row] = s;
        min_d2[row] = 0x7f800000u;   // +inf bits
    }
}

// ---------------------------------------------------------------------------
// Kernel 0b: single-block community bucketing, 1024 threads.
__global__ __launch_bounds__(1024)
void bucket_kernel(const int* __restrict__ comm,
                   int* __restrict__ offs,      // [N_COMM+1]
                   int* __restrict__ members) { // [N_NODES]
    __shared__ int scnt[N_COMM];
    __shared__ int scur[N_COMM];
    const int tid = threadIdx.x;
    if (tid < N_COMM) scnt[tid] = 0;
    __syncthreads();
    for (int i = tid; i < N_NODES; i += 1024) atomicAdd(&scnt[comm[i]], 1);
    __syncthreads();
    if (tid == 0) {
        int acc = 0;
        for (int c = 0; c < N_COMM; ++c) { scur[c] = acc; offs[c] = acc; acc += scnt[c]; }
        offs[N_COMM] = acc;
    }
    __syncthreads();
    for (int i = tid; i < N_NODES; i += 1024) {
        int p = atomicAdd(&scur[comm[i]], 1);
        members[p] = i;
    }
}

// ---------------------------------------------------------------------------
// Kernel 1: MFMA X·X^T (bf16 hi/lo), TRIANGULAR grid (by<=bx), extracting both
// column-min (-> min_d2[j0+..]) and row-min (-> min_d2[i0+..]) per tile.
// C/D layout (m74/m101): col = lane&31, row = (reg&3) + 8*(reg>>2) + 4*(lane>>5).
__global__ __launch_bounds__(256, 2)
void minneg_mfma_kernel(const unsigned short* __restrict__ xhi,
                        const unsigned short* __restrict__ xlo,
                        const int* __restrict__ comm,
                        const float* __restrict__ sq,
                        unsigned int* __restrict__ min_d2) {
    if (blockIdx.y > blockIdx.x) return;   // triangular: rows-block >= cols-block

    __shared__ __align__(16) unsigned short lds[4][128][LDS_STR];  // 72 KB
    __shared__ unsigned int colmin[128];

    const int tid  = threadIdx.x;
    const int lane = tid & 63;
    const int w    = tid >> 6;
    const int wr   = w >> 1, wc = w & 1;    // wave position in 2x2 grid of 64x64
    const int lr   = lane & 31;
    const int lh   = lane >> 5;
    const int i0   = blockIdx.x * 128;      // A rows
    const int j0   = blockIdx.y * 128;      // B rows (= output cols)

    if (tid < 128) colmin[tid] = 0x7f800000u;

    f32x16 acc[2][2];
    #pragma unroll
    for (int g = 0; g < 2; ++g)
        #pragma unroll
        for (int h = 0; h < 2; ++h)
            #pragma unroll
            for (int e = 0; e < 16; ++e) acc[g][h][e] = 0.f;

    #pragma unroll
    for (int kh = 0; kh < 2; ++kh) {
        __syncthreads();
        #pragma unroll
        for (int it = 0; it < 16; ++it) {
            int g    = tid + it * 256;          // 0..4095
            int tile = g >> 10;                 // 0..3
            int row  = (g >> 3) & 127;
            int seg  = g & 7;
            const unsigned short* src = (tile & 1) ? xlo : xhi;
            int rbase = (tile & 2) ? j0 : i0;
            uint4 v = *(const uint4*)&src[(size_t)(rbase + row) * DIM + kh * 64 + seg * 8];
            *(uint4*)&lds[tile][row][seg * 8] = v;
        }
        __syncthreads();

        #pragma unroll
        for (int ks = 0; ks < 4; ++ks) {
            const int kb = ks * 16 + lh * 8;
            bf16x8 ahi[2], alo[2], bhi[2], blo[2];
            #pragma unroll
            for (int g = 0; g < 2; ++g) {
                ahi[g] = *(const bf16x8*)&lds[0][wr * 64 + g * 32 + lr][kb];
                alo[g] = *(const bf16x8*)&lds[1][wr * 64 + g * 32 + lr][kb];
            }
            #pragma unroll
            for (int h = 0; h < 2; ++h) {
                bhi[h] = *(const bf16x8*)&lds[2][wc * 64 + h * 32 + lr][kb];
                blo[h] = *(const bf16x8*)&lds[3][wc * 64 + h * 32 + lr][kb];
            }
            #pragma unroll
            for (int g = 0; g < 2; ++g)
                #pragma unroll
                for (int h = 0; h < 2; ++h) {
                    acc[g][h] = __builtin_amdgcn_mfma_f32_32x32x16_bf16(
                        ahi[g], bhi[h], acc[g][h], 0, 0, 0);
                    acc[g][h] = __builtin_amdgcn_mfma_f32_32x32x16_bf16(
                        ahi[g], blo[h], acc[g][h], 0, 0, 0);
                    acc[g][h] = __builtin_amdgcn_mfma_f32_32x32x16_bf16(
                        alo[g], bhi[h], acc[g][h], 0, 0, 0);
                }
        }
    }

    // ---- epilogue: d2 = sq_i + sq_j - 2*dot ; col-min AND row-min over negatives
    int   civ[2][4][4];
    float sqv[2][4][4];
    #pragma unroll
    for (int g = 0; g < 2; ++g)
        #pragma unroll
        for (int q = 0; q < 4; ++q) {
            int rb = i0 + wr * 64 + g * 32 + 4 * lh + 8 * q;
            *(int4*)&civ[g][q][0]   = *(const int4*)&comm[rb];
            *(float4*)&sqv[g][q][0] = *(const float4*)&sq[rb];
        }

    const float FINF = __uint_as_float(0x7f800000u);
    float rmin[2][16];
    #pragma unroll
    for (int g = 0; g < 2; ++g)
        #pragma unroll
        for (int e = 0; e < 16; ++e) rmin[g][e] = FINF;

    #pragma unroll
    for (int h = 0; h < 2; ++h) {
        int colt = wc * 64 + h * 32 + lr;
        int j  = j0 + colt;
        int cj = comm[j];
        float sqj = sq[j];
        float cmin = FINF;
        #pragma unroll
        for (int g = 0; g < 2; ++g)
            #pragma unroll
            for (int q = 0; q < 4; ++q)
                #pragma unroll
                for (int t = 0; t < 4; ++t) {
                    float d2 = fmaxf(sqv[g][q][t] + sqj - 2.f * acc[g][h][q * 4 + t], 0.f);
                    if (civ[g][q][t] != cj) {
                        cmin = fminf(cmin, d2);
                        rmin[g][q * 4 + t] = fminf(rmin[g][q * 4 + t], d2);
                    }
                }
        cmin = fminf(cmin, __shfl_xor(cmin, 32));
        if (lh == 0) atomicMin(&colmin[colt], __float_as_uint(cmin));
    }

    // row-min: scatter per-thread partials into LDS overlay, then 128-thread reduce
    __syncthreads();                          // all fragment reads of lds done
    float (*rowpart)[RP_STR] = (float (*)[RP_STR])lds;   // 128 x 68 floats (34.8 KB)
    #pragma unroll
    for (int g = 0; g < 2; ++g)
        #pragma unroll
        for (int q = 0; q < 4; ++q)
            #pragma unroll
            for (int t = 0; t < 4; ++t) {
                int rowl = wr * 64 + g * 32 + 4 * lh + 8 * q + t;
                rowpart[rowl][wc * 32 + lr] = rmin[g][q * 4 + t];
            }
    __syncthreads();
    if (tid < 128) {
        float m = FINF;
        #pragma unroll
        for (int k = 0; k < 16; ++k) {
            float4 v = *(const float4*)&rowpart[tid][k * 4];
            m = fminf(m, fminf(fminf(v.x, v.y), fminf(v.z, v.w)));
        }
        atomicMin(&min_d2[i0 + tid], __float_as_uint(m));
        atomicMin(&min_d2[j0 + tid], colmin[tid]);
    }
}

// ---------------------------------------------------------------------------
// Kernel 2: positives via community-gathered MFMA Gram. One block per community.
__global__ __launch_bounds__(256, 2)
void pos_mfma_kernel(const unsigned short* __restrict__ xhi,
                     const unsigned short* __restrict__ xlo,
                     const float* __restrict__ sq,
                     const unsigned int* __restrict__ min_d2,
                     const int* __restrict__ offs,
                     const int* __restrict__ members,
                     double* __restrict__ psum,
                     unsigned int* __restrict__ pcnt) {
    __shared__ __align__(16) unsigned short lds[4][128][LDS_STR];  // 72 KB
    __shared__ float sqA[128], sqB[128], mnA[128];   // mnA: minneg dist, or -1 if no neg
    __shared__ double sred[4];
    __shared__ unsigned int cred[4];

    const int tid  = threadIdx.x;
    const int lane = tid & 63;
    const int w    = tid >> 6;
    const int wr   = w >> 1, wc = w & 1;
    const int lr   = lane & 31;
    const int lh   = lane >> 5;

    const int c    = blockIdx.x;
    const int beg  = offs[c], end = offs[c + 1];
    const int size = end - beg;
    const int nt   = (size + 127) >> 7;

    float tsum = 0.f;
    unsigned int tcnt = 0u;
    const float FINF = __uint_as_float(0x7f800000u);

    for (int tr = 0; tr < nt; ++tr)
    for (int tc = 0; tc < nt; ++tc) {
        __syncthreads();    // previous tile's epilogue LDS reads done
        // stage per-row attrs
        if (tid < 128) {
            int ii = beg + tr * 128 + tid;
            if (ii < end) {
                int ia = members[ii];
                sqA[tid] = sq[ia];
                unsigned int mb = min_d2[ia];
                mnA[tid] = (mb == 0x7f800000u) ? -1.f
                         : sqrtf(fmaxf(__uint_as_float(mb), 0.f));
            } else { sqA[tid] = 0.f; mnA[tid] = -1.f; }
        } else {
            int t2 = tid - 128;
            int jj = beg + tc * 128 + t2;
            sqB[t2] = (jj < end) ? sq[members[jj]] : 0.f;
        }

        f32x16 acc[2][2];
        #pragma unroll
        for (int g = 0; g < 2; ++g)
            #pragma unroll
            for (int h = 0; h < 2; ++h)
                #pragma unroll
                for (int e = 0; e < 16; ++e) acc[g][h][e] = 0.f;

        for (int kh = 0; kh < 2; ++kh) {
            __syncthreads();
            #pragma unroll
            for (int it = 0; it < 16; ++it) {
                int g    = tid + it * 256;
                int tile = g >> 10;
                int row  = (g >> 3) & 127;
                int seg  = g & 7;
                int mi   = beg + ((tile & 2) ? tc : tr) * 128 + row;
                int node = (mi < end) ? members[mi] : 0;    // dummy; masked later
                const unsigned short* src = (tile & 1) ? xlo : xhi;
                uint4 v = *(const uint4*)&src[(size_t)node * DIM + kh * 64 + seg * 8];
                *(uint4*)&lds[tile][row][seg * 8] = v;
            }
            __syncthreads();

            #pragma unroll
            for (int ks = 0; ks < 4; ++ks) {
                const int kb = ks * 16 + lh * 8;
                bf16x8 ahi[2], alo[2], bhi[2], blo[2];
                #pragma unroll
                for (int g = 0; g < 2; ++g) {
                    ahi[g] = *(const bf16x8*)&lds[0][wr * 64 + g * 32 + lr][kb];
                    alo[g] = *(const bf16x8*)&lds[1][wr * 64 + g * 32 + lr][kb];
                }
                #pragma unroll
                for (int h = 0; h < 2; ++h) {
                    bhi[h] = *(const bf16x8*)&lds[2][wc * 64 + h * 32 + lr][kb];
                    blo[h] = *(const bf16x8*)&lds[3][wc * 64 + h * 32 + lr][kb];
                }
                #pragma unroll
                for (int g = 0; g < 2; ++g)
                    #pragma unroll
                    for (int h = 0; h < 2; ++h) {
                        acc[g][h] = __builtin_amdgcn_mfma_f32_32x32x16_bf16(
                            ahi[g], bhi[h], acc[g][h], 0, 0, 0);
                        acc[g][h] = __builtin_amdgcn_mfma_f32_32x32x16_bf16(
                            ahi[g], blo[h], acc[g][h], 0, 0, 0);
                        acc[g][h] = __builtin_amdgcn_mfma_f32_32x32x16_bf16(
                            alo[g], bhi[h], acc[g][h], 0, 0, 0);
                    }
            }
        }

        // epilogue: tl over valid (i,j) pairs of this tile
        #pragma unroll
        for (int h = 0; h < 2; ++h) {
            int coll = wc * 64 + h * 32 + lr;
            int jv   = tc * 128 + coll;
            float sqj = sqB[coll];
            #pragma unroll
            for (int g = 0; g < 2; ++g)
                #pragma unroll
                for (int q = 0; q < 4; ++q)
                    #pragma unroll
                    for (int t = 0; t < 4; ++t) {
                        int rowl = wr * 64 + g * 32 + 4 * lh + 8 * q + t;
                        int iv   = tr * 128 + rowl;
                        float mn = mnA[rowl];
                        if (iv < size && jv < size && iv != jv && mn >= 0.f) {
                            float d2 = sqA[rowl] + sqj - 2.f * acc[g][h][q * 4 + t];
                            float dist = sqrtf(fmaxf(d2, 0.f));
                            tsum += fmaxf(dist - mn + MARGIN, 0.f);
                            tcnt += 1u;
                        }
                    }
        }
        (void)FINF;
    }

    // block reduce -> per-community partial
    #pragma unroll
    for (int off = 32; off > 0; off >>= 1) {
        tsum += __shfl_down(tsum, off);
        tcnt += __shfl_down(tcnt, off);
    }
    if (lane == 0) { sred[w] = (double)tsum; cred[w] = tcnt; }
    __syncthreads();
    if (tid == 0) {
        psum[c] = sred[0] + sred[1] + sred[2] + sred[3];
        pcnt[c] = cred[0] + cred[1] + cred[2] + cred[3];
    }
}

// ---------------------------------------------------------------------------
// Kernel 3: reduce 100 community partials -> final mean.
__global__ __launch_bounds__(256)
void finalize_kernel(const double* __restrict__ psum,
                     const unsigned int* __restrict__ pcnt,
                     float* __restrict__ out) {
    __shared__ double       ds[256];
    __shared__ unsigned int cs[256];
    const int t = threadIdx.x;
    double s = 0.0; unsigned int c = 0u;
    for (int b = t; b < N_COMM; b += 256) { s += psum[b]; c += pcnt[b]; }
    ds[t] = s; cs[t] = c;
    __syncthreads();
    for (int off = 128; off > 0; off >>= 1) {
        if (t < off) { ds[t] += ds[t + off]; cs[t] += cs[t + off]; }
        __syncthreads();
    }
    if (t == 0) out[0] = (cs[0] > 0u) ? (float)(ds[0] / (double)cs[0]) : 0.f;
}

// ---------------------------------------------------------------------------
extern "C" void kernel_launch(void* const* d_in, const int* in_sizes, int n_in,
                              void* d_out, int out_size, void* d_ws, size_t ws_size,
                              hipStream_t stream) {
    const float* x    = (const float*)d_in[0];
    const int*   comm = (const int*)d_in[1];
    float*       out  = (float*)d_out;

    // workspace layout (bytes):
    //       0 float  sq[8192]           32768
    //   32768 uint   min_d2[8192]       32768
    //   65536 int    offs[101]            512 (padded)
    //   66048 int    members[8192]      32768
    //   98816 double psum[100]           1024 (padded)
    //   99840 uint   pcnt[100]            512 (padded)
    //  100352 ushort xhi[8192*128]    2097152
    // 2197504 ushort xlo[8192*128]    2097152   (total ~4.1 MB)
    char* ws = (char*)d_ws;
    float*          sq      = (float*)(ws);
    unsigned int*   min_d2  = (unsigned int*)(ws + 32768);
    int*            offs    = (int*)(ws + 65536);
    int*            members = (int*)(ws + 66048);
    double*         psum    = (double*)(ws + 98816);
    unsigned int*   pcnt    = (unsigned int*)(ws + 99840);
    unsigned short* xhi     = (unsigned short*)(ws + 100352);
    unsigned short* xlo     = (unsigned short*)(ws + 2197504);

    convert_sq_kernel<<<N_NODES / 4, 256, 0, stream>>>(x, xhi, xlo, sq, min_d2);

    bucket_kernel<<<1, 1024, 0, stream>>>(comm, offs, members);

    dim3 g1(N_NODES / 128, N_NODES / 128);   // 64x64, lower triangle computes
    minneg_mfma_kernel<<<g1, 256, 0, stream>>>(xhi, xlo, comm, sq, min_d2);

    pos_mfma_kernel<<<N_COMM, 256, 0, stream>>>(xhi, xlo, sq, min_d2, offs, members,
                                                psum, pcnt);

    finalize_kernel<<<1, 256, 0, stream>>>(psum, pcnt, out);
}

// Round 5
// 134.773 us; speedup vs baseline: 6.7581x; 1.0508x over previous
//
#include <hip/hip_runtime.h>

#define N_NODES 8192
#define DIM     128
#define N_COMM  100
#define MARGIN  1.0f

// minneg: 128x128 block tile, 4 waves of 64x64, mfma 32x32x16 bf16, K staged
// in 32-wide quarters. LDS stride 40 shorts = 80 B = 5*16B (odd quad stride ->
// measured-conflict-free class for b128 wave reads).
#define KQ       32
#define LDS_STR  40
// pos kernel keeps K=64 halves (latency-bound, fewer barriers)
#define LDS_STRP 72
#define RP_STR   68               // row-min partial stride (floats)

typedef __attribute__((ext_vector_type(8)))  short bf16x8;
typedef __attribute__((ext_vector_type(16))) float f32x16;

__device__ inline unsigned short f32_to_bf16_rne(float f) {
    unsigned u = __float_as_uint(f);
    unsigned r = u + 0x7fffu + ((u >> 16) & 1u);
    return (unsigned short)(r >> 16);
}
__device__ inline float bf16_to_f32(unsigned short h) {
    return __uint_as_float(((unsigned)h) << 16);
}

// ---------------------------------------------------------------------------
// Kernel 0 (merged): blocks 0..2047 = bf16 hi/lo split + row sq norms + min_d2
// init (wave per row); block 2048 = community bucketing.
__global__ __launch_bounds__(256)
void prep_kernel(const float* __restrict__ x,
                 const int* __restrict__ comm,
                 unsigned short* __restrict__ xhi,
                 unsigned short* __restrict__ xlo,
                 float* __restrict__ sq,
                 unsigned int* __restrict__ min_d2,
                 int* __restrict__ offs,
                 int* __restrict__ members) {
    __shared__ int scnt[N_COMM];
    __shared__ int scur[N_COMM];
    const int tid = threadIdx.x;

    if (blockIdx.x < 2048) {
        int row  = blockIdx.x * 4 + (tid >> 6);
        int lane = tid & 63;
        const float* p = x + (size_t)row * DIM;
        float v0 = p[lane], v1 = p[lane + 64];
        unsigned short h0 = f32_to_bf16_rne(v0), h1 = f32_to_bf16_rne(v1);
        unsigned short l0 = f32_to_bf16_rne(v0 - bf16_to_f32(h0));
        unsigned short l1 = f32_to_bf16_rne(v1 - bf16_to_f32(h1));
        size_t base = (size_t)row * DIM;
        xhi[base + lane] = h0;  xhi[base + 64 + lane] = h1;
        xlo[base + lane] = l0;  xlo[base + 64 + lane] = l1;
        float s = v0 * v0 + v1 * v1;
        #pragma unroll
        for (int off = 32; off > 0; off >>= 1) s += __shfl_down(s, off);
        if (lane == 0) {
            sq[row] = s;
            min_d2[row] = 0x7f800000u;   // +inf bits
        }
        return;
    }

    // ---- bucketing block
    if (tid < N_COMM) scnt[tid] = 0;
    __syncthreads();
    for (int i = tid; i < N_NODES; i += 256) atomicAdd(&scnt[comm[i]], 1);
    __syncthreads();
    if (tid == 0) {
        int acc = 0;
        for (int c = 0; c < N_COMM; ++c) { scur[c] = acc; offs[c] = acc; acc += scnt[c]; }
        offs[N_COMM] = acc;
    }
    __syncthreads();
    for (int i = tid; i < N_NODES; i += 256) {
        int p = atomicAdd(&scur[comm[i]], 1);
        members[p] = i;
    }
}

// ---------------------------------------------------------------------------
// Kernel 1: MFMA X·X^T (bf16 hi/lo), exact triangular grid (2080 blocks),
// K staged in 32-quarters (41.4 KB LDS -> 3 blocks/CU), col-min AND row-min.
// C/D layout (m74/m101): col = lane&31, row = (reg&3) + 8*(reg>>2) + 4*(lane>>5).
__global__ __launch_bounds__(256, 3)
void minneg_mfma_kernel(const unsigned short* __restrict__ xhi,
                        const unsigned short* __restrict__ xlo,
                        const int* __restrict__ comm,
                        const float* __restrict__ sq,
                        unsigned int* __restrict__ min_d2) {
    __shared__ __align__(16) unsigned short lds[4][128][LDS_STR];  // 40960 B
    __shared__ unsigned int colmin[128];

    // linear -> lower-triangle (bx >= by)
    const int b = blockIdx.x;
    int bx = (int)((sqrtf(8.f * (float)b + 1.f) - 1.f) * 0.5f);
    while ((bx + 1) * (bx + 2) / 2 <= b) ++bx;
    while (bx * (bx + 1) / 2 > b) --bx;
    const int by = b - bx * (bx + 1) / 2;

    const int tid  = threadIdx.x;
    const int lane = tid & 63;
    const int w    = tid >> 6;
    const int wr   = w >> 1, wc = w & 1;
    const int lr   = lane & 31;
    const int lh   = lane >> 5;
    const int i0   = bx * 128;      // A rows
    const int j0   = by * 128;      // B rows (= output cols)

    if (tid < 128) colmin[tid] = 0x7f800000u;

    f32x16 acc[2][2];
    #pragma unroll
    for (int g = 0; g < 2; ++g)
        #pragma unroll
        for (int h = 0; h < 2; ++h)
            #pragma unroll
            for (int e = 0; e < 16; ++e) acc[g][h][e] = 0.f;

    #pragma unroll
    for (int kq = 0; kq < 4; ++kq) {
        __syncthreads();
        // stage 4 tiles x 128 rows x 32 bf16: 2048 16B-chunks, 8 per thread
        #pragma unroll
        for (int it = 0; it < 8; ++it) {
            int g    = tid + it * 256;          // 0..2047
            int tile = g >> 9;                  // 0..3
            int row  = (g >> 2) & 127;
            int seg  = g & 3;
            const unsigned short* src = (tile & 1) ? xlo : xhi;
            int rbase = (tile & 2) ? j0 : i0;
            uint4 v = *(const uint4*)&src[(size_t)(rbase + row) * DIM + kq * KQ + seg * 8];
            *(uint4*)&lds[tile][row][seg * 8] = v;
        }
        __syncthreads();

        #pragma unroll
        for (int ks = 0; ks < 2; ++ks) {
            const int kb = ks * 16 + lh * 8;
            bf16x8 ahi[2], alo[2], bhi[2], blo[2];
            #pragma unroll
            for (int g = 0; g < 2; ++g) {
                ahi[g] = *(const bf16x8*)&lds[0][wr * 64 + g * 32 + lr][kb];
                alo[g] = *(const bf16x8*)&lds[1][wr * 64 + g * 32 + lr][kb];
            }
            #pragma unroll
            for (int h = 0; h < 2; ++h) {
                bhi[h] = *(const bf16x8*)&lds[2][wc * 64 + h * 32 + lr][kb];
                blo[h] = *(const bf16x8*)&lds[3][wc * 64 + h * 32 + lr][kb];
            }
            #pragma unroll
            for (int g = 0; g < 2; ++g)
                #pragma unroll
                for (int h = 0; h < 2; ++h) {
                    acc[g][h] = __builtin_amdgcn_mfma_f32_32x32x16_bf16(
                        ahi[g], bhi[h], acc[g][h], 0, 0, 0);
                    acc[g][h] = __builtin_amdgcn_mfma_f32_32x32x16_bf16(
                        ahi[g], blo[h], acc[g][h], 0, 0, 0);
                    acc[g][h] = __builtin_amdgcn_mfma_f32_32x32x16_bf16(
                        alo[g], bhi[h], acc[g][h], 0, 0, 0);
                }
        }
    }

    // ---- epilogue: d2 = sq_i + sq_j - 2*dot ; col-min AND row-min over negatives
    int   civ[2][4][4];
    float sqv[2][4][4];
    #pragma unroll
    for (int g = 0; g < 2; ++g)
        #pragma unroll
        for (int q = 0; q < 4; ++q) {
            int rb = i0 + wr * 64 + g * 32 + 4 * lh + 8 * q;
            *(int4*)&civ[g][q][0]   = *(const int4*)&comm[rb];
            *(float4*)&sqv[g][q][0] = *(const float4*)&sq[rb];
        }

    const float FINF = __uint_as_float(0x7f800000u);
    float rmin[2][16];
    #pragma unroll
    for (int g = 0; g < 2; ++g)
        #pragma unroll
        for (int e = 0; e < 16; ++e) rmin[g][e] = FINF;

    #pragma unroll
    for (int h = 0; h < 2; ++h) {
        int colt = wc * 64 + h * 32 + lr;
        int j  = j0 + colt;
        int cj = comm[j];
        float sqj = sq[j];
        float cmin = FINF;
        #pragma unroll
        for (int g = 0; g < 2; ++g)
            #pragma unroll
            for (int q = 0; q < 4; ++q)
                #pragma unroll
                for (int t = 0; t < 4; ++t) {
                    float d2 = fmaxf(sqv[g][q][t] + sqj - 2.f * acc[g][h][q * 4 + t], 0.f);
                    if (civ[g][q][t] != cj) {
                        cmin = fminf(cmin, d2);
                        rmin[g][q * 4 + t] = fminf(rmin[g][q * 4 + t], d2);
                    }
                }
        cmin = fminf(cmin, __shfl_xor(cmin, 32));
        if (lh == 0) atomicMin(&colmin[colt], __float_as_uint(cmin));
    }

    // row-min: scatter per-thread partials into LDS overlay, then 128-thread reduce
    __syncthreads();
    float (*rowpart)[RP_STR] = (float (*)[RP_STR])lds;   // 128 x 68 floats (34.8 KB)
    #pragma unroll
    for (int g = 0; g < 2; ++g)
        #pragma unroll
        for (int q = 0; q < 4; ++q)
            #pragma unroll
            for (int t = 0; t < 4; ++t) {
                int rowl = wr * 64 + g * 32 + 4 * lh + 8 * q + t;
                rowpart[rowl][wc * 32 + lr] = rmin[g][q * 4 + t];
            }
    __syncthreads();
    if (tid < 128) {
        float m = FINF;
        #pragma unroll
        for (int k = 0; k < 16; ++k) {
            float4 v = *(const float4*)&rowpart[tid][k * 4];
            m = fminf(m, fminf(fminf(v.x, v.y), fminf(v.z, v.w)));
        }
        atomicMin(&min_d2[i0 + tid], __float_as_uint(m));
        atomicMin(&min_d2[j0 + tid], colmin[tid]);
    }
}

// ---------------------------------------------------------------------------
// Kernel 2: positives via community-gathered MFMA Gram, one block/community,
// with wave-uniform subtile guards (skip 32-subtiles beyond community size).
__global__ __launch_bounds__(256, 2)
void pos_mfma_kernel(const unsigned short* __restrict__ xhi,
                     const unsigned short* __restrict__ xlo,
                     const float* __restrict__ sq,
                     const unsigned int* __restrict__ min_d2,
                     const int* __restrict__ offs,
                     const int* __restrict__ members,
                     double* __restrict__ psum,
                     unsigned int* __restrict__ pcnt) {
    __shared__ __align__(16) unsigned short lds[4][128][LDS_STRP];  // 72 KB
    __shared__ float sqA[128], sqB[128], mnA[128];
    __shared__ double sred[4];
    __shared__ unsigned int cred[4];

    const int tid  = threadIdx.x;
    const int lane = tid & 63;
    const int w    = tid >> 6;
    const int wr   = w >> 1, wc = w & 1;
    const int lr   = lane & 31;
    const int lh   = lane >> 5;

    const int c    = blockIdx.x;
    const int beg  = offs[c], end = offs[c + 1];
    const int size = end - beg;
    const int nt   = (size + 127) >> 7;

    float tsum = 0.f;
    unsigned int tcnt = 0u;

    for (int tr = 0; tr < nt; ++tr)
    for (int tc = 0; tc < nt; ++tc) {
        // wave-uniform validity of this wave's 32-subtiles
        bool av[2], bv[2];
        #pragma unroll
        for (int g = 0; g < 2; ++g) av[g] = (tr * 128 + wr * 64 + g * 32) < size;
        #pragma unroll
        for (int h = 0; h < 2; ++h) bv[h] = (tc * 128 + wc * 64 + h * 32) < size;

        __syncthreads();    // previous tile's epilogue LDS reads done
        if (tid < 128) {
            int ii = beg + tr * 128 + tid;
            if (ii < end) {
                int ia = members[ii];
                sqA[tid] = sq[ia];
                unsigned int mb = min_d2[ia];
                mnA[tid] = (mb == 0x7f800000u) ? -1.f
                         : sqrtf(fmaxf(__uint_as_float(mb), 0.f));
            } else { sqA[tid] = 0.f; mnA[tid] = -1.f; }
        } else {
            int t2 = tid - 128;
            int jj = beg + tc * 128 + t2;
            sqB[t2] = (jj < end) ? sq[members[jj]] : 0.f;
        }

        f32x16 acc[2][2];
        #pragma unroll
        for (int g = 0; g < 2; ++g)
            #pragma unroll
            for (int h = 0; h < 2; ++h)
                #pragma unroll
                for (int e = 0; e < 16; ++e) acc[g][h][e] = 0.f;

        for (int kh = 0; kh < 2; ++kh) {
            __syncthreads();
            #pragma unroll
            for (int it = 0; it < 16; ++it) {
                int g    = tid + it * 256;
                int tile = g >> 10;
                int row  = (g >> 3) & 127;
                int seg  = g & 7;
                int mi   = beg + ((tile & 2) ? tc : tr) * 128 + row;
                int node = (mi < end) ? members[mi] : 0;
                const unsigned short* src = (tile & 1) ? xlo : xhi;
                uint4 v = *(const uint4*)&src[(size_t)node * DIM + kh * 64 + seg * 8];
                *(uint4*)&lds[tile][row][seg * 8] = v;
            }
            __syncthreads();

            #pragma unroll
            for (int ks = 0; ks < 4; ++ks) {
                const int kb = ks * 16 + lh * 8;
                bf16x8 ahi[2], alo[2], bhi[2], blo[2];
                #pragma unroll
                for (int g = 0; g < 2; ++g) if (av[g]) {
                    ahi[g] = *(const bf16x8*)&lds[0][wr * 64 + g * 32 + lr][kb];
                    alo[g] = *(const bf16x8*)&lds[1][wr * 64 + g * 32 + lr][kb];
                }
                #pragma unroll
                for (int h = 0; h < 2; ++h) if (bv[h]) {
                    bhi[h] = *(const bf16x8*)&lds[2][wc * 64 + h * 32 + lr][kb];
                    blo[h] = *(const bf16x8*)&lds[3][wc * 64 + h * 32 + lr][kb];
                }
                #pragma unroll
                for (int g = 0; g < 2; ++g)
                    #pragma unroll
                    for (int h = 0; h < 2; ++h) if (av[g] && bv[h]) {
                        acc[g][h] = __builtin_amdgcn_mfma_f32_32x32x16_bf16(
                            ahi[g], bhi[h], acc[g][h], 0, 0, 0);
                        acc[g][h] = __builtin_amdgcn_mfma_f32_32x32x16_bf16(
                            ahi[g], blo[h], acc[g][h], 0, 0, 0);
                        acc[g][h] = __builtin_amdgcn_mfma_f32_32x32x16_bf16(
                            alo[g], bhi[h], acc[g][h], 0, 0, 0);
                    }
            }
        }

        // epilogue: tl over valid (i,j) pairs of this tile
        #pragma unroll
        for (int h = 0; h < 2; ++h) {
            if (!bv[h]) continue;
            int coll = wc * 64 + h * 32 + lr;
            int jv   = tc * 128 + coll;
            float sqj = sqB[coll];
            #pragma unroll
            for (int g = 0; g < 2; ++g) {
                if (!av[g]) continue;
                #pragma unroll
                for (int q = 0; q < 4; ++q)
                    #pragma unroll
                    for (int t = 0; t < 4; ++t) {
                        int rowl = wr * 64 + g * 32 + 4 * lh + 8 * q + t;
                        int iv   = tr * 128 + rowl;
                        float mn = mnA[rowl];
                        if (iv < size && jv < size && iv != jv && mn >= 0.f) {
                            float d2 = sqA[rowl] + sqj - 2.f * acc[g][h][q * 4 + t];
                            float dist = sqrtf(fmaxf(d2, 0.f));
                            tsum += fmaxf(dist - mn + MARGIN, 0.f);
                            tcnt += 1u;
                        }
                    }
            }
        }
    }

    // block reduce -> per-community partial
    #pragma unroll
    for (int off = 32; off > 0; off >>= 1) {
        tsum += __shfl_down(tsum, off);
        tcnt += __shfl_down(tcnt, off);
    }
    if (lane == 0) { sred[w] = (double)tsum; cred[w] = tcnt; }
    __syncthreads();
    if (tid == 0) {
        psum[c] = sred[0] + sred[1] + sred[2] + sred[3];
        pcnt[c] = cred[0] + cred[1] + cred[2] + cred[3];
    }
}

// ---------------------------------------------------------------------------
// Kernel 3: reduce 100 community partials -> final mean.
__global__ __launch_bounds__(256)
void finalize_kernel(const double* __restrict__ psum,
                     const unsigned int* __restrict__ pcnt,
                     float* __restrict__ out) {
    __shared__ double       ds[256];
    __shared__ unsigned int cs[256];
    const int t = threadIdx.x;
    double s = 0.0; unsigned int c = 0u;
    for (int b = t; b < N_COMM; b += 256) { s += psum[b]; c += pcnt[b]; }
    ds[t] = s; cs[t] = c;
    __syncthreads();
    for (int off = 128; off > 0; off >>= 1) {
        if (t < off) { ds[t] += ds[t + off]; cs[t] += cs[t + off]; }
        __syncthreads();
    }
    if (t == 0) out[0] = (cs[0] > 0u) ? (float)(ds[0] / (double)cs[0]) : 0.f;
}

// ---------------------------------------------------------------------------
extern "C" void kernel_launch(void* const* d_in, const int* in_sizes, int n_in,
                              void* d_out, int out_size, void* d_ws, size_t ws_size,
                              hipStream_t stream) {
    const float* x    = (const float*)d_in[0];
    const int*   comm = (const int*)d_in[1];
    float*       out  = (float*)d_out;

    // workspace layout (bytes):
    //       0 float  sq[8192]           32768
    //   32768 uint   min_d2[8192]       32768
    //   65536 int    offs[101]            512 (padded)
    //   66048 int    members[8192]      32768
    //   98816 double psum[100]           1024 (padded)
    //   99840 uint   pcnt[100]            512 (padded)
    //  100352 ushort xhi[8192*128]    2097152
    // 2197504 ushort xlo[8192*128]    2097152   (total ~4.1 MB)
    char* ws = (char*)d_ws;
    float*          sq      = (float*)(ws);
    unsigned int*   min_d2  = (unsigned int*)(ws + 32768);
    int*            offs    = (int*)(ws + 65536);
    int*            members = (int*)(ws + 66048);
    double*         psum    = (double*)(ws + 98816);
    unsigned int*   pcnt    = (unsigned int*)(ws + 99840);
    unsigned short* xhi     = (unsigned short*)(ws + 100352);
    unsigned short* xlo     = (unsigned short*)(ws + 2197504);

    prep_kernel<<<2049, 256, 0, stream>>>(x, comm, xhi, xlo, sq, min_d2,
                                          offs, members);

    const int ntri = (N_NODES / 128) * (N_NODES / 128 + 1) / 2;   // 2080
    minneg_mfma_kernel<<<ntri, 256, 0, stream>>>(xhi, xlo, comm, sq, min_d2);

    pos_mfma_kernel<<<N_COMM, 256, 0, stream>>>(xhi, xlo, sq, min_d2, offs, members,
                                                psum, pcnt);

    finalize_kernel<<<1, 256, 0, stream>>>(psum, pcnt, out);
}